// Round 16
// baseline (1108.294 us; speedup 1.0000x reference)
//
#include <hip/hip_runtime.h>

typedef _Float16 half8 __attribute__((ext_vector_type(8)));
typedef float f32x4 __attribute__((ext_vector_type(4)));

namespace {
constexpr int kB = 2048;
constexpr int kT = 72;
constexpr int kI = 200;
constexpr int kH = 200;
constexpr int kO = 53;
constexpr int kG = 600;      // 3*kH
constexpr int BT = 8;        // batch rows per WG (8 -> 256 WGs -> all 256 CUs)
constexpr int NWG = kB / BT; // 256
constexpr int MT = 38;       // M tiles of 16 covering 608 (600 padded)
constexpr int KS = 7;        // K slices of 32 covering 224 (200 padded)
constexpr int GSTR = 18;     // LDS G col stride

// ws layout (float offsets) — identical to R4/R9/R13
constexpr int XW1    = 0;          // [2048][600] emb@Wih1^T + bih1
constexpr int WIH1T  = 1228800;    // [200][600] Wih1^T (prep only)
constexpr int FCINT  = 1348800;    // [200][200] fc_in_W^T (prep only)
constexpr int F0     = 1388800;    // fp16 A-frags: hh1, ih2, hh2, ih3, hh3
constexpr int FSZ    = 68096;      // floats per frag matrix
constexpr int FHEAD  = F0 + 5 * FSZ;
constexpr int PERM   = MT * KS * 64;

// output offsets (floats)
constexpr int OH1 = kB * kT * kO;  // 7815168
constexpr int OH2 = OH1 + kB * kH;
constexpr int OH3 = OH2 + kB * kH;
}

__device__ __forceinline__ float sig_(float x) { return 1.0f / (1.0f + __expf(-x)); }
__device__ __forceinline__ float tanh_(float x) {
    return 1.0f - 2.0f / (__expf(2.0f * x) + 1.0f);
}

// barrier draining LDS only; in-flight global weight loads survive (validated R6/R9/R12/R13/R15).
__device__ __forceinline__ void barx() {
    asm volatile("s_waitcnt lgkmcnt(0)\n\ts_barrier" ::: "memory");
}

// fp16 fragment-order shadow write of h element (n, j); n < BT
__device__ __forceinline__ void store_fb(_Float16* fb, int n, int j, float v) {
    int ks = j >> 5, r = j & 31;
    fb[((ks << 6) + ((r >> 3) << 4) + n) * 8 + (r & 7)] = (_Float16)v;
}

// ---------------- prep kernels (identical to R4/R9/R13) ----------------

__global__ __launch_bounds__(256) void prep_transpose2(
    const float* __restrict__ Wih1, const float* __restrict__ fciW,
    float* __restrict__ ws) {
    int idx = blockIdx.x * 256 + threadIdx.x;
    if (idx < 120000) {
        int k = idx / kG, c = idx - k * kG;
        ws[WIH1T + idx] = Wih1[c * kI + k];
    } else {
        int i = idx - 120000;
        if (i < 40000) {
            int k = i / kH, h = i - k * kH;
            ws[FCINT + i] = fciW[h * kI + k];
        }
    }
}

__global__ __launch_bounds__(256) void prep_frags(
    const float* __restrict__ Whh1, const float* __restrict__ Wih2,
    const float* __restrict__ Whh2, const float* __restrict__ Wih3,
    const float* __restrict__ Whh3, const float* __restrict__ fcoW,
    float* __restrict__ ws) {
    int idx = blockIdx.x * 256 + threadIdx.x;
    const float* src; int R; long long dstHalf; int rem;
    if (idx < 5 * PERM) {
        int m = idx / PERM; rem = idx - m * PERM;
        switch (m) {
            case 0: src = Whh1; break;
            case 1: src = Wih2; break;
            case 2: src = Whh2; break;
            case 3: src = Wih3; break;
            default: src = Whh3; break;
        }
        R = kG; dstHalf = 2LL * (F0 + m * FSZ);
    } else {
        rem = idx - 5 * PERM;
        if (rem >= 4 * KS * 64) return;
        src = fcoW; R = kO; dstHalf = 2LL * FHEAD;
    }
    int lane = rem & 63;
    int tmp = rem >> 6;
    int ks = tmp % KS;
    int mt = tmp / KS;
    int row = mt * 16 + (lane & 15);
    int k0 = ks * 32 + (lane >> 4) * 8;
    half8 v;
    #pragma unroll
    for (int j = 0; j < 8; ++j) {
        int k = k0 + j;
        v[j] = (_Float16)((row < R && k < kH) ? src[row * kH + k] : 0.0f);
    }
    *(half8*)((_Float16*)ws + dstHalf + (long long)rem * 8) = v;
}

__global__ __launch_bounds__(256) void prep_input(
    const float* __restrict__ enc,
    const float* __restrict__ bn_g, const float* __restrict__ bn_b,
    const float* __restrict__ bn_m, const float* __restrict__ bn_v,
    const float* __restrict__ fcib, const float* __restrict__ bih1,
    float* ws) {
    __shared__ float xh[kI];
    __shared__ float emb[kH];
    const int b = blockIdx.x, tid = threadIdx.x;
    const float* fcInT = ws + FCINT;
    const float* Wih1T = ws + WIH1T;
    if (tid < kI) {
        float x = enc[b * kI + tid];
        xh[tid] = (x - bn_m[tid]) * rsqrtf(bn_v[tid] + 1e-5f) * bn_g[tid] + bn_b[tid];
    }
    __syncthreads();
    if (tid < kH) {
        float s = fcib[tid];
        for (int k = 0; k < kI; ++k) s = fmaf(xh[k], fcInT[k * kH + tid], s);
        emb[tid] = fmaxf(s, 0.0f);
    }
    __syncthreads();
    for (int c = tid; c < kG; c += 256) {
        float s = bih1[c];
        for (int k = 0; k < kH; ++k) s = fmaf(emb[k], Wih1T[k * kG + c], s);
        ws[XW1 + b * kG + c] = s;
    }
}

// ---------------- main persistent GRU kernel ----------------
// 256 WGs x 1024 threads (16 waves), one per CU. WG owns 8 batch rows.
// R15 bodies, restructured into a 4-barrier/step pipeline exploiting the
// dependency slack M1(t+1) <- U1(t):
//   P1: M2(t)->Gs  ||  M1(t+1)->Gs1  ||  head(t-1)   (flat 80-item deal)
//   P2: U2(t) ; U1(t+1)
//   P3: M3(t)->Gs/Gns
//   P4: U3(t)
// Prologue: M1(0)+U1(0). Epilogue: head(kT-1) + final states.
__global__ __launch_bounds__(1024, 4) void gru_main(
    const float* __restrict__ ws,
    const float* __restrict__ h1in, const float* __restrict__ h2in,
    const float* __restrict__ h3in,
    const float* __restrict__ bhh1,
    const float* __restrict__ bih2, const float* __restrict__ bhh2,
    const float* __restrict__ bih3, const float* __restrict__ bhh3,
    const float* __restrict__ fcob,
    float* __restrict__ out) {
    __shared__ float xwL[kG * BT];                         // 19200 B, [j][n]
    __shared__ __align__(16) _Float16 fb1[KS * 64 * 8];    // 7168 B each
    __shared__ __align__(16) _Float16 fb2[KS * 64 * 8];
    __shared__ __align__(16) _Float16 fb3[KS * 64 * 8];
    __shared__ float Gs[608 * GSTR];                       // 43776 B (L2/L3 gates)
    __shared__ float Gs1[608 * GSTR];                      // 43776 B (L1 lookahead gates)
    __shared__ float Gns[208 * GSTR];                      // 14976 B
    __shared__ float bias[9 * kH];                         // 7200 B
    __shared__ float hb[64];
    // total ~147 KB -> 1 WG/CU

    const int tid = threadIdx.x, wv = tid >> 6, ln = tid & 63;
    const int lb = ln >> 4, lr = ln & 15;
    const int b0 = blockIdx.x * BT;
    const bool lo = (ln < 16);
    half8 z8;
    #pragma unroll
    for (int j = 0; j < 8; ++j) z8[j] = (_Float16)0.0f;

    // ---- zero ALL fb slots first (garbage batch-cols 8..15 + K-pad become 0)
    {
        float4* f1 = (float4*)fb1;
        float4* f2 = (float4*)fb2;
        float4* f3 = (float4*)fb3;
        const float4 z4 = {0.f, 0.f, 0.f, 0.f};
        for (int i = tid; i < KS * 64 * 8 * 2 / 16; i += 1024) {
            f1[i] = z4; f2[i] = z4; f3[i] = z4;
        }
    }
    // ---- stage xw1 (time-invariant) into LDS, folding bhh1 r/z biases
    for (int i = tid; i < kG * BT; i += 1024) {
        int n = i / kG, j = i - n * kG;
        float v = ws[XW1 + (b0 + n) * kG + j];
        if (j < 2 * kH) v += bhh1[j];
        xwL[j * BT + n] = v;
    }
    // ---- biases: [0]=b1n [1]=b2r [2]=b2z [3]=b2xn [4]=b2hn [5..8]=L3
    for (int i = tid; i < 9 * kH; i += 1024) {
        int c = i / kH, j = i - c * kH;
        float v;
        switch (c) {
            case 0:  v = bhh1[2 * kH + j]; break;
            case 1:  v = bih2[j] + bhh2[j]; break;
            case 2:  v = bih2[kH + j] + bhh2[kH + j]; break;
            case 3:  v = bih2[2 * kH + j]; break;
            case 4:  v = bhh2[2 * kH + j]; break;
            case 5:  v = bih3[j] + bhh3[j]; break;
            case 6:  v = bih3[kH + j] + bhh3[kH + j]; break;
            case 7:  v = bih3[2 * kH + j]; break;
            default: v = bhh3[2 * kH + j]; break;
        }
        bias[i] = v;
    }
    if (tid < 64) hb[tid] = (tid < kO) ? fcob[tid] : 0.0f;
    __syncthreads();   // fb zeroing complete before shadow writes

    // ---- h states -> registers + fp16 frag shadows (BT*kH = 1600 elems)
    float h1r[2], h2r[2], h3r[2];
    #pragma unroll
    for (int s = 0; s < 2; ++s) {
        int idx = tid + s * 1024;
        if (idx < BT * kH) {
            int n = idx & 7, j = idx >> 3;
            h1r[s] = h1in[(b0 + n) * kH + j];
            h2r[s] = h2in[(b0 + n) * kH + j];
            h3r[s] = h3in[(b0 + n) * kH + j];
            store_fb(fb1, n, j, h1r[s]);
            store_fb(fb2, n, j, h2r[s]);
            store_fb(fb3, n, j, h3r[s]);
        } else { h1r[s] = h2r[s] = h3r[s] = 0.0f; }
    }
    __syncthreads();

    const half8* WFhh1 = (const half8*)(ws + F0);
    const half8* WFih2 = (const half8*)(ws + F0 + FSZ);
    const half8* WFhh2 = (const half8*)(ws + F0 + 2 * FSZ);
    const half8* WFih3 = (const half8*)(ws + F0 + 3 * FSZ);
    const half8* WFhh3 = (const half8*)(ws + F0 + 4 * FSZ);
    const half8* WFhead = (const half8*)(ws + FHEAD);

    // ================= prologue: M1(0) -> Gs1, then U1(0) =================
    {
        half8 bf[KS];
        #pragma unroll
        for (int ks = 0; ks < KS; ++ks)
            bf[ks] = *(const half8*)(fb1 + (ks * 64 + ln) * 8);
        for (int mt = wv; mt < MT; mt += 16) {
            const half8* wp = WFhh1 + (mt * KS) * 64 + ln;
            f32x4 acc = {0.f, 0.f, 0.f, 0.f};
            #pragma unroll
            for (int ks = 0; ks < KS - 1; ++ks)
                acc = __builtin_amdgcn_mfma_f32_16x16x32_f16(wp[ks * 64], bf[ks], acc, 0, 0, 0);
            half8 w6 = z8;
            if (lo) w6 = wp[(KS - 1) * 64];
            acc = __builtin_amdgcn_mfma_f32_16x16x32_f16(w6, bf[KS - 1], acc, 0, 0, 0);
            int row = mt * 16 + lb * 4;
            #pragma unroll
            for (int rg = 0; rg < 4; ++rg) Gs1[(row + rg) * GSTR + lr] = acc[rg];
        }
    }
    barx();
    #pragma unroll
    for (int s = 0; s < 2; ++s) {
        int idx = tid + s * 1024;
        if (idx < BT * kH) {
            int n = idx & 7, j = idx >> 3;
            float r  = sig_(xwL[j * BT + n]            + Gs1[j * GSTR + n]);
            float z  = sig_(xwL[(kH + j) * BT + n]     + Gs1[(kH + j) * GSTR + n]);
            float nn = tanh_(xwL[(2 * kH + j) * BT + n] + r * (Gs1[(2 * kH + j) * GSTR + n] + bias[j]));
            h1r[s] = (1.0f - z) * nn + z * h1r[s];
            store_fb(fb1, n, j, h1r[s]);
        }
    }
    barx();

    // ================= main loop: 4 barriers/step =================
    for (int t = 0; t < kT; ++t) {
        const bool doM1 = (t + 1 < kT);
        // ---------- P1: M2(t) [items 0-37] || M1(t+1) [38-75] || head(t-1) [76-79] ----------
        {
            half8 bx[KS], bh[KS];
            #pragma unroll
            for (int ks = 0; ks < KS; ++ks) {
                bx[ks] = *(const half8*)(fb1 + (ks * 64 + ln) * 8);
                bh[ks] = *(const half8*)(fb2 + (ks * 64 + ln) * 8);
            }
            for (int item = wv; item < 80; item += 16) {
                if (item < 38) {
                    const int mt = item;
                    const half8* wpx = WFih2 + (mt * KS) * 64 + ln;
                    const half8* wph = WFhh2 + (mt * KS) * 64 + ln;
                    f32x4 ax = {0.f, 0.f, 0.f, 0.f}, ah = {0.f, 0.f, 0.f, 0.f};
                    #pragma unroll
                    for (int ks = 0; ks < KS - 1; ++ks) {
                        ax = __builtin_amdgcn_mfma_f32_16x16x32_f16(wpx[ks * 64], bx[ks], ax, 0, 0, 0);
                        ah = __builtin_amdgcn_mfma_f32_16x16x32_f16(wph[ks * 64], bh[ks], ah, 0, 0, 0);
                    }
                    half8 wx6 = z8, wh6 = z8;
                    if (lo) { wx6 = wpx[(KS - 1) * 64]; wh6 = wph[(KS - 1) * 64]; }
                    ax = __builtin_amdgcn_mfma_f32_16x16x32_f16(wx6, bx[KS - 1], ax, 0, 0, 0);
                    ah = __builtin_amdgcn_mfma_f32_16x16x32_f16(wh6, bh[KS - 1], ah, 0, 0, 0);
                    int row = mt * 16 + lb * 4;
                    if (mt < 25) {
                        #pragma unroll
                        for (int rg = 0; rg < 4; ++rg) Gs[(row + rg) * GSTR + lr] = ax[rg] + ah[rg];
                    } else {
                        #pragma unroll
                        for (int rg = 0; rg < 4; ++rg) {
                            Gs[(row + rg) * GSTR + lr] = ax[rg];
                            Gns[(row - 400 + rg) * GSTR + lr] = ah[rg];
                        }
                    }
                } else if (item < 76) {
                    if (doM1) {
                        const int mt = item - 38;
                        const half8* wp = WFhh1 + (mt * KS) * 64 + ln;
                        f32x4 acc = {0.f, 0.f, 0.f, 0.f};
                        #pragma unroll
                        for (int ks = 0; ks < KS - 1; ++ks)
                            acc = __builtin_amdgcn_mfma_f32_16x16x32_f16(wp[ks * 64], bx[ks], acc, 0, 0, 0);
                        half8 w6 = z8;
                        if (lo) w6 = wp[(KS - 1) * 64];
                        acc = __builtin_amdgcn_mfma_f32_16x16x32_f16(w6, bx[KS - 1], acc, 0, 0, 0);
                        int row = mt * 16 + lb * 4;
                        #pragma unroll
                        for (int rg = 0; rg < 4; ++rg) Gs1[(row + rg) * GSTR + lr] = acc[rg];
                    }
                } else {
                    if (t > 0) {
                        const int hw = item - 76;
                        const half8* wp = WFhead + (hw * KS) * 64 + ln;
                        f32x4 acc = {0.f, 0.f, 0.f, 0.f};
                        #pragma unroll
                        for (int ks = 0; ks < KS - 1; ++ks) {
                            half8 b = *(const half8*)(fb3 + (ks * 64 + ln) * 8);
                            acc = __builtin_amdgcn_mfma_f32_16x16x32_f16(wp[ks * 64], b, acc, 0, 0, 0);
                        }
                        {
                            half8 w6 = z8;
                            if (lo) w6 = wp[(KS - 1) * 64];
                            half8 b = *(const half8*)(fb3 + ((KS - 1) * 64 + ln) * 8);
                            acc = __builtin_amdgcn_mfma_f32_16x16x32_f16(w6, b, acc, 0, 0, 0);
                        }
                        if (lr < BT) {
                            int o0 = hw * 16 + lb * 4;
                            int obase = (b0 + lr) * (kT * kO) + (t - 1) * kO;
                            #pragma unroll
                            for (int rg = 0; rg < 4; ++rg) {
                                int o = o0 + rg;
                                if (o < kO) out[obase + o] = sig_(acc[rg] + hb[o]);
                            }
                        }
                    }
                }
            }
        }
        barx();
        // ---------- P2: U2(t), then U1(t+1) ----------
        #pragma unroll
        for (int s = 0; s < 2; ++s) {
            int idx = tid + s * 1024;
            if (idx < BT * kH) {
                int n = idx & 7, j = idx >> 3;
                float r  = sig_(Gs[j * GSTR + n]            + bias[kH + j]);
                float z  = sig_(Gs[(kH + j) * GSTR + n]     + bias[2 * kH + j]);
                float nn = tanh_(Gs[(2 * kH + j) * GSTR + n] + bias[3 * kH + j]
                                 + r * (Gns[j * GSTR + n]   + bias[4 * kH + j]));
                h2r[s] = (1.0f - z) * nn + z * h2r[s];
                store_fb(fb2, n, j, h2r[s]);
            }
        }
        if (doM1) {
            #pragma unroll
            for (int s = 0; s < 2; ++s) {
                int idx = tid + s * 1024;
                if (idx < BT * kH) {
                    int n = idx & 7, j = idx >> 3;
                    float r  = sig_(xwL[j * BT + n]            + Gs1[j * GSTR + n]);
                    float z  = sig_(xwL[(kH + j) * BT + n]     + Gs1[(kH + j) * GSTR + n]);
                    float nn = tanh_(xwL[(2 * kH + j) * BT + n] + r * (Gs1[(2 * kH + j) * GSTR + n] + bias[j]));
                    h1r[s] = (1.0f - z) * nn + z * h1r[s];
                    store_fb(fb1, n, j, h1r[s]);
                }
            }
        }
        barx();
        // ---------- P3: M3(t) ----------
        {
            half8 bx[KS], bh[KS];
            #pragma unroll
            for (int ks = 0; ks < KS; ++ks) {
                bx[ks] = *(const half8*)(fb2 + (ks * 64 + ln) * 8);
                bh[ks] = *(const half8*)(fb3 + (ks * 64 + ln) * 8);
            }
            for (int mt = wv; mt < MT; mt += 16) {
                const half8* wpx = WFih3 + (mt * KS) * 64 + ln;
                const half8* wph = WFhh3 + (mt * KS) * 64 + ln;
                f32x4 ax = {0.f, 0.f, 0.f, 0.f}, ah = {0.f, 0.f, 0.f, 0.f};
                #pragma unroll
                for (int ks = 0; ks < KS - 1; ++ks) {
                    ax = __builtin_amdgcn_mfma_f32_16x16x32_f16(wpx[ks * 64], bx[ks], ax, 0, 0, 0);
                    ah = __builtin_amdgcn_mfma_f32_16x16x32_f16(wph[ks * 64], bh[ks], ah, 0, 0, 0);
                }
                half8 wx6 = z8, wh6 = z8;
                if (lo) { wx6 = wpx[(KS - 1) * 64]; wh6 = wph[(KS - 1) * 64]; }
                ax = __builtin_amdgcn_mfma_f32_16x16x32_f16(wx6, bx[KS - 1], ax, 0, 0, 0);
                ah = __builtin_amdgcn_mfma_f32_16x16x32_f16(wh6, bh[KS - 1], ah, 0, 0, 0);
                int row = mt * 16 + lb * 4;
                if (mt < 25) {
                    #pragma unroll
                    for (int rg = 0; rg < 4; ++rg) Gs[(row + rg) * GSTR + lr] = ax[rg] + ah[rg];
                } else {
                    #pragma unroll
                    for (int rg = 0; rg < 4; ++rg) {
                        Gs[(row + rg) * GSTR + lr] = ax[rg];
                        Gns[(row - 400 + rg) * GSTR + lr] = ah[rg];
                    }
                }
            }
        }
        barx();
        // ---------- P4: U3(t) ----------
        #pragma unroll
        for (int s = 0; s < 2; ++s) {
            int idx = tid + s * 1024;
            if (idx < BT * kH) {
                int n = idx & 7, j = idx >> 3;
                float r  = sig_(Gs[j * GSTR + n]            + bias[5 * kH + j]);
                float z  = sig_(Gs[(kH + j) * GSTR + n]     + bias[6 * kH + j]);
                float nn = tanh_(Gs[(2 * kH + j) * GSTR + n] + bias[7 * kH + j]
                                 + r * (Gns[j * GSTR + n]   + bias[8 * kH + j]));
                h3r[s] = (1.0f - z) * nn + z * h3r[s];
                store_fb(fb3, n, j, h3r[s]);
            }
        }
        barx();
    }

    // ---------- epilogue: head(kT-1) on waves 0-3 ----------
    if (wv < 4) {
        const half8* wp = WFhead + (wv * KS) * 64 + ln;
        f32x4 acc = {0.f, 0.f, 0.f, 0.f};
        #pragma unroll
        for (int ks = 0; ks < KS - 1; ++ks) {
            half8 b = *(const half8*)(fb3 + (ks * 64 + ln) * 8);
            acc = __builtin_amdgcn_mfma_f32_16x16x32_f16(wp[ks * 64], b, acc, 0, 0, 0);
        }
        {
            half8 w6 = z8;
            if (lo) w6 = wp[(KS - 1) * 64];
            half8 b = *(const half8*)(fb3 + ((KS - 1) * 64 + ln) * 8);
            acc = __builtin_amdgcn_mfma_f32_16x16x32_f16(w6, b, acc, 0, 0, 0);
        }
        if (lr < BT) {
            int o0 = wv * 16 + lb * 4;
            int obase = (b0 + lr) * (kT * kO) + (kT - 1) * kO;
            #pragma unroll
            for (int rg = 0; rg < 4; ++rg) {
                int o = o0 + rg;
                if (o < kO) out[obase + o] = sig_(acc[rg] + hb[o]);
            }
        }
    }

    // ---- final hidden states: stage in LDS (Gs) for coalesced global writes
    #pragma unroll
    for (int s = 0; s < 2; ++s) {
        int idx = tid + s * 1024;
        if (idx < BT * kH) {
            Gs[idx] = h1r[s];
            Gs[1600 + idx] = h2r[s];
            Gs[3200 + idx] = h3r[s];
        }
    }
    __syncthreads();
    for (int i = tid; i < BT * kH; i += 1024) {
        int n = i / kH, j = i - n * kH;
        int src = j * BT + n;
        out[OH1 + (b0 + n) * kH + j] = Gs[src];
        out[OH2 + (b0 + n) * kH + j] = Gs[1600 + src];
        out[OH3 + (b0 + n) * kH + j] = Gs[3200 + src];
    }
}

extern "C" void kernel_launch(void* const* d_in, const int* in_sizes, int n_in,
                              void* d_out, int out_size, void* d_ws, size_t ws_size,
                              hipStream_t stream) {
    (void)in_sizes; (void)n_in; (void)out_size; (void)ws_size;
    const float* enc  = (const float*)d_in[0];
    const float* h1in = (const float*)d_in[1];
    const float* h2in = (const float*)d_in[2];
    const float* h3in = (const float*)d_in[3];
    const float* bn_g = (const float*)d_in[4];
    const float* bn_b = (const float*)d_in[5];
    const float* bn_m = (const float*)d_in[6];
    const float* bn_v = (const float*)d_in[7];
    const float* fciW = (const float*)d_in[8];
    const float* fcib = (const float*)d_in[9];
    const float* Wih1 = (const float*)d_in[10];
    const float* Whh1 = (const float*)d_in[11];
    const float* bih1 = (const float*)d_in[12];
    const float* bhh1 = (const float*)d_in[13];
    const float* Wih2 = (const float*)d_in[14];
    const float* Whh2 = (const float*)d_in[15];
    const float* bih2 = (const float*)d_in[16];
    const float* bhh2 = (const float*)d_in[17];
    const float* Wih3 = (const float*)d_in[18];
    const float* Whh3 = (const float*)d_in[19];
    const float* bih3 = (const float*)d_in[20];
    const float* bhh3 = (const float*)d_in[21];
    const float* fcoW = (const float*)d_in[22];
    const float* fcob = (const float*)d_in[23];
    float* ws  = (float*)d_ws;
    float* out = (float*)d_out;

    hipLaunchKernelGGL(prep_transpose2, dim3(625), dim3(256), 0, stream, Wih1, fciW, ws);
    hipLaunchKernelGGL(prep_frags, dim3(340), dim3(256), 0, stream,
                       Whh1, Wih2, Whh2, Wih3, Whh3, fcoW, ws);
    hipLaunchKernelGGL(prep_input, dim3(kB), dim3(256), 0, stream,
                       enc, bn_g, bn_b, bn_m, bn_v, fcib, bih1, ws);
    hipLaunchKernelGGL(gru_main, dim3(NWG), dim3(1024), 0, stream,
                       ws, h1in, h2in, h3in, bhh1, bih2, bhh2, bih3, bhh3, fcob, out);
}